// Round 6
// baseline (77.686 us; speedup 1.0000x reference)
//
#include <hip/hip_runtime.h>
#include <math.h>

#define NROWS   96
#define DIM     768
#define THRESH  0.3f
#define NPAIR   4560            // 96*95/2
#define PTOT    9120            // 2*NPAIR
#define QTOT    9216            // 96*96
#define NBLK    576
#define NWAVES  (NBLK * 4)      // 2304 = 96 rows x 24 strips
#define SPR     24              // 4-col strips per 96-col row
#define MAGIC   0x13579BDFu     // != 0xAAAAAAAA ws poison

// ws layout (bytes):
//   pos[9120] f32 @0      | neg[9216] f32 @36480   (rare-path only)
//   slotSp[576] f32 @73344 | slotSn[576] f32 @75648
//   slotMx[576] f32 @77952 | slotMn[576] f32 @80256
//   flags[576]  u32 @82560                           (poison != MAGIC)

__device__ __forceinline__ float d12(
    const float4& x0, const float4& x1, const float4& x2,
    const float4& y0, const float4& y1, const float4& y2)
{
    return x0.x*y0.x + x0.y*y0.y + x0.z*y0.z + x0.w*y0.w
         + x1.x*y1.x + x1.y*y1.y + x1.z*y1.z + x1.w*y1.w
         + x2.x*y2.x + x2.y*y2.y + x2.z*y2.z + x2.w*y2.w;
}

template <int N>
__device__ __forceinline__ void wreduce(float* v)
{
#pragma unroll
    for (int off = 32; off; off >>= 1) {
#pragma unroll
        for (int k = 0; k < N; k++) v[k] += __shfl_down(v[k], off);
    }
}

// Single kernel: gram strips with inline norms -> per-block slots -> release
// flag; block 0 spin-acquires all flags, reduces, analytic hinge, finalize.
// sum max(0, n-p+T) = P*Sn - Q*Sp + P*Q*T + sum relu(p - T - n)
// (correction exactly 0 unless pmax - nmin > T; exact fallback kept)
__global__ __launch_bounds__(256) void fused_kernel(
    const float* __restrict__ stereos, const float* __restrict__ astereos,
    float* __restrict__ pos, float* __restrict__ neg,
    float* __restrict__ slotSp, float* __restrict__ slotSn,
    float* __restrict__ slotMx, float* __restrict__ slotMn,
    unsigned* __restrict__ flags, float* __restrict__ out)
{
    __shared__ float  sSp[4], sSn[4], sMx[4], sMn[4];
    __shared__ double rsp[4], rsn[4], redd[4];
    __shared__ float  rmx[4], rmn[4];
    __shared__ double bcd[2];
    __shared__ float  bnmin;
    __shared__ int    rare;

    int tid  = threadIdx.x;
    int wave = tid >> 6, lane = tid & 63;
    int gw = blockIdx.x * 4 + wave;                // 0..2303
    int i  = gw / SPR;                             // 0..95
    int j0 = (gw - i * SPR) * 4;                   // 0..92

    // ---- fused S+C strips: shared b rows = stereos[j0..j0+3] ----
    // acc: [0]=saaS [1]=saaC [2+m]=sbb [6+m]=sabS [10+m]=sabC
    float acc[13];
    {
        const float4* aS = (const float4*)(stereos  + i * DIM);
        const float4* aC = (const float4*)(astereos + i * DIM);
        float4 as0 = aS[lane], as1 = aS[lane + 64], as2 = aS[lane + 128];
        float4 ac0 = aC[lane], ac1 = aC[lane + 64], ac2 = aC[lane + 128];
        acc[0] = d12(as0, as1, as2, as0, as1, as2);
        acc[1] = d12(ac0, ac1, ac2, ac0, ac1, ac2);
#pragma unroll
        for (int m = 0; m < 4; m++) {
            const float4* b = (const float4*)(stereos + (j0 + m) * DIM);
            float4 b0 = b[lane], b1 = b[lane + 64], b2 = b[lane + 128];
            acc[2 + m]  = d12(b0, b1, b2, b0, b1, b2);
            acc[6 + m]  = d12(as0, as1, as2, b0, b1, b2);
            acc[10 + m] = d12(ac0, ac1, ac2, b0, b1, b2);
        }
        wreduce<13>(acc);
    }
    // ---- A strip (astereos triu), reversed id for load balance ----
    int sw = NWAVES - 1 - gw;
    int ia = sw / SPR, ja0 = (sw - ia * SPR) * 4;
    float accA[9];                                 // [0]=saaA [1+m]=sbbA [5+m]=sabA
    {
        const float4* aA = (const float4*)(astereos + ia * DIM);
        float4 a0 = aA[lane], a1 = aA[lane + 64], a2 = aA[lane + 128];
        accA[0] = d12(a0, a1, a2, a0, a1, a2);
#pragma unroll
        for (int m = 0; m < 4; m++) {
            const float4* b = (const float4*)(astereos + (ja0 + m) * DIM);
            float4 b0 = b[lane], b1 = b[lane + 64], b2 = b[lane + 128];
            accA[1 + m] = d12(b0, b1, b2, b0, b1, b2);
            accA[5 + m] = d12(a0, a1, a2, b0, b1, b2);
        }
        wreduce<9>(accA);
    }

    if (lane == 0) {
        float wsp = 0.f, wsn = 0.f, wmx = -INFINITY, wmn = INFINITY;
        float invaS = 1.0f / fmaxf(sqrtf(acc[0]), 1e-8f);
        float invaC = 1.0f / fmaxf(sqrtf(acc[1]), 1e-8f);
        int baseS = (i * (191 - i)) / 2 - i - 1;   // tri idx = baseS + j
#pragma unroll
        for (int m = 0; m < 4; m++) {
            float invb = 1.0f / fmaxf(sqrtf(acc[2 + m]), 1e-8f);
            float sc = acc[10 + m] * invaC * invb;          // neg sim
            neg[i * NROWS + j0 + m] = sc;
            wsn += sc; wmn = fminf(wmn, sc);
            if (j0 + m > i) {                               // pos sim (S)
                float ss = acc[6 + m] * invaS * invb;
                pos[baseS + j0 + m] = ss;
                wsp += ss; wmx = fmaxf(wmx, ss);
            }
        }
        float invaA = 1.0f / fmaxf(sqrtf(accA[0]), 1e-8f);
        int baseA = (ia * (191 - ia)) / 2 - ia - 1;
#pragma unroll
        for (int m = 0; m < 4; m++) {
            if (ja0 + m > ia) {                             // pos sim (A)
                float invb = 1.0f / fmaxf(sqrtf(accA[1 + m]), 1e-8f);
                float sa = accA[5 + m] * invaA * invb;
                pos[NPAIR + baseA + ja0 + m] = sa;
                wsp += sa; wmx = fmaxf(wmx, sa);
            }
        }
        sSp[wave] = wsp; sSn[wave] = wsn; sMx[wave] = wmx; sMn[wave] = wmn;
    }
    __syncthreads();
    if (tid == 0) {
        slotSp[blockIdx.x] = sSp[0] + sSp[1] + sSp[2] + sSp[3];
        slotSn[blockIdx.x] = sSn[0] + sSn[1] + sSn[2] + sSn[3];
        slotMx[blockIdx.x] = fmaxf(fmaxf(sMx[0], sMx[1]), fmaxf(sMx[2], sMx[3]));
        slotMn[blockIdx.x] = fminf(fminf(sMn[0], sMn[1]), fminf(sMn[2], sMn[3]));
        __threadfence();                                    // order slot stores
        __hip_atomic_store(&flags[blockIdx.x], MAGIC,
                           __ATOMIC_RELEASE, __HIP_MEMORY_SCOPE_AGENT);
    }
    if (blockIdx.x != 0) return;

    // ---- block 0: spin-acquire all flags (blocks retire -> no deadlock) ----
    for (int f = tid; f < NBLK; f += 256)
        while (__hip_atomic_load(&flags[f], __ATOMIC_ACQUIRE,
                                 __HIP_MEMORY_SCOPE_AGENT) != MAGIC)
            __builtin_amdgcn_s_sleep(2);
    __syncthreads();

    double sp = 0.0, sn = 0.0;
    float mx = -INFINITY, mn = INFINITY;
    for (int f = tid; f < NBLK; f += 256) {
        sp += (double)__hip_atomic_load(&slotSp[f], __ATOMIC_RELAXED,
                                        __HIP_MEMORY_SCOPE_AGENT);
        sn += (double)__hip_atomic_load(&slotSn[f], __ATOMIC_RELAXED,
                                        __HIP_MEMORY_SCOPE_AGENT);
        mx = fmaxf(mx, __hip_atomic_load(&slotMx[f], __ATOMIC_RELAXED,
                                         __HIP_MEMORY_SCOPE_AGENT));
        mn = fminf(mn, __hip_atomic_load(&slotMn[f], __ATOMIC_RELAXED,
                                         __HIP_MEMORY_SCOPE_AGENT));
    }
    for (int off = 32; off; off >>= 1) {
        sp += __shfl_down(sp, off);
        sn += __shfl_down(sn, off);
        mx = fmaxf(mx, __shfl_down(mx, off));
        mn = fminf(mn, __shfl_down(mn, off));
    }
    if (lane == 0) { rsp[wave] = sp; rsn[wave] = sn;
                     rmx[wave] = mx; rmn[wave] = mn; }
    __syncthreads();
    if (tid == 0) {
        bcd[0] = rsp[0] + rsp[1] + rsp[2] + rsp[3];          // Sp
        bcd[1] = rsn[0] + rsn[1] + rsn[2] + rsn[3];          // Sn
        float pm = fmaxf(fmaxf(rmx[0], rmx[1]), fmaxf(rmx[2], rmx[3]));
        float nm = fminf(fminf(rmn[0], rmn[1]), fminf(rmn[2], rmn[3]));
        bnmin = nm;
        rare = (pm - nm > THRESH) ? 1 : 0;
    }
    __syncthreads();

    double corr = 0.0;
    if (rare) {                                              // exact fallback
        float nmv = bnmin;
        for (int p = tid; p < PTOT; p += 256) {
            float pv = __hip_atomic_load(&pos[p], __ATOMIC_RELAXED,
                                         __HIP_MEMORY_SCOPE_AGENT);
            if (pv - nmv > THRESH) {
                for (int q = 0; q < QTOT; q++) {
                    float nv = __hip_atomic_load(&neg[q], __ATOMIC_RELAXED,
                                                 __HIP_MEMORY_SCOPE_AGENT);
                    float d = pv - THRESH - nv;
                    if (d > 0.f) corr += (double)d;
                }
            }
        }
    }
    for (int off = 32; off; off >>= 1) corr += __shfl_down(corr, off);
    if (lane == 0) redd[wave] = corr;
    __syncthreads();
    if (tid == 0) {
        corr = redd[0] + redd[1] + redd[2] + redd[3];
        double PQ = (double)PTOT * (double)QTOT;
        double total = (double)PTOT * bcd[1] - (double)QTOT * bcd[0]
                     + PQ * (double)THRESH + corr;
        out[0] = (float)(total / PQ);
    }
}

extern "C" void kernel_launch(void* const* d_in, const int* in_sizes, int n_in,
                              void* d_out, int out_size, void* d_ws, size_t ws_size,
                              hipStream_t stream)
{
    const float* stereos  = (const float*)d_in[0];
    const float* astereos = (const float*)d_in[1];

    char* ws = (char*)d_ws;
    float*    pos    = (float*)ws;
    float*    neg    = (float*)(ws + 36480);
    float*    slotSp = (float*)(ws + 73344);
    float*    slotSn = (float*)(ws + 75648);
    float*    slotMx = (float*)(ws + 77952);
    float*    slotMn = (float*)(ws + 80256);
    unsigned* flags  = (unsigned*)(ws + 82560);
    float*    out    = (float*)d_out;

    fused_kernel<<<NBLK, 256, 0, stream>>>(stereos, astereos, pos, neg,
                                           slotSp, slotSn, slotMx, slotMn,
                                           flags, out);
}

// Round 7
// 61.546 us; speedup vs baseline: 1.2623x; 1.2623x over previous
//
#include <hip/hip_runtime.h>
#include <math.h>

#define NROWS   96
#define DIM     768
#define THRESH  0.3f
#define NPAIR   4560            // 96*95/2
#define PTOT    9120            // 2*NPAIR
#define QTOT    9216            // 96*96
#define NBLK    576
#define NWAVES  (NBLK * 4)      // 2304 = 96 rows x 24 strips
#define SPR     24              // 4-col strips per 96-col row

// ws layout (bytes):
//   pos[9120] f32 @0      | neg[9216] f32 @36480   (scaled sims; rare-path only)
//   slotSp[576] f32 @73344 | slotSn[576] f32 @75648
//   slotMx[576] f32 @77952 | slotMn[576] f32 @80256

__device__ __forceinline__ float d12(
    const float4& x0, const float4& x1, const float4& x2,
    const float4& y0, const float4& y1, const float4& y2)
{
    return x0.x*y0.x + x0.y*y0.y + x0.z*y0.z + x0.w*y0.w
         + x1.x*y1.x + x1.y*y1.y + x1.z*y1.z + x1.w*y1.w
         + x2.x*y2.x + x2.y*y2.y + x2.z*y2.z + x2.w*y2.w;
}

template <int N>
__device__ __forceinline__ void wreduce(float* v)
{
#pragma unroll
    for (int off = 32; off; off >>= 1) {
#pragma unroll
        for (int k = 0; k < N; k++) v[k] += __shfl_down(v[k], off);
    }
}

// ---- K1: gram strips with inline norms -> scaled sims + per-block slots ----
// Fused S+C strips share b-rows (stereos j0..j0+3): 11 row-loads/wave.
// Publish via kernel boundary (no atomics, no flags — R6 lesson: spin-wait
// barriers cost ~10us; kernel boundaries ~3us).
__global__ __launch_bounds__(256) void gram_kernel(
    const float* __restrict__ stereos, const float* __restrict__ astereos,
    float* __restrict__ pos, float* __restrict__ neg,
    float* __restrict__ slotSp, float* __restrict__ slotSn,
    float* __restrict__ slotMx, float* __restrict__ slotMn)
{
    __shared__ float sSp[4], sSn[4], sMx[4], sMn[4];

    int tid  = threadIdx.x;
    int wave = tid >> 6, lane = tid & 63;
    int gw = blockIdx.x * 4 + wave;                // 0..2303
    int i  = gw / SPR;                             // 0..95
    int j0 = (gw - i * SPR) * 4;                   // 0..92

    // fused S+C strips: acc [0]=saaS [1]=saaC [2+m]=sbb [6+m]=sabS [10+m]=sabC
    float acc[13];
    {
        const float4* aS = (const float4*)(stereos  + i * DIM);
        const float4* aC = (const float4*)(astereos + i * DIM);
        float4 as0 = aS[lane], as1 = aS[lane + 64], as2 = aS[lane + 128];
        float4 ac0 = aC[lane], ac1 = aC[lane + 64], ac2 = aC[lane + 128];
        acc[0] = d12(as0, as1, as2, as0, as1, as2);
        acc[1] = d12(ac0, ac1, ac2, ac0, ac1, ac2);
#pragma unroll
        for (int m = 0; m < 4; m++) {
            const float4* b = (const float4*)(stereos + (j0 + m) * DIM);
            float4 b0 = b[lane], b1 = b[lane + 64], b2 = b[lane + 128];
            acc[2 + m]  = d12(b0, b1, b2, b0, b1, b2);
            acc[6 + m]  = d12(as0, as1, as2, b0, b1, b2);
            acc[10 + m] = d12(ac0, ac1, ac2, b0, b1, b2);
        }
        wreduce<13>(acc);
    }
    // A strip (astereos triu), reversed id for load balance
    int sw = NWAVES - 1 - gw;
    int ia = sw / SPR, ja0 = (sw - ia * SPR) * 4;
    float accA[9];                                 // [0]=saaA [1+m]=sbbA [5+m]=sabA
    {
        const float4* aA = (const float4*)(astereos + ia * DIM);
        float4 a0 = aA[lane], a1 = aA[lane + 64], a2 = aA[lane + 128];
        accA[0] = d12(a0, a1, a2, a0, a1, a2);
#pragma unroll
        for (int m = 0; m < 4; m++) {
            const float4* b = (const float4*)(astereos + (ja0 + m) * DIM);
            float4 b0 = b[lane], b1 = b[lane + 64], b2 = b[lane + 128];
            accA[1 + m] = d12(b0, b1, b2, b0, b1, b2);
            accA[5 + m] = d12(a0, a1, a2, b0, b1, b2);
        }
        wreduce<9>(accA);
    }

    if (lane == 0) {
        float wsp = 0.f, wsn = 0.f, wmx = -INFINITY, wmn = INFINITY;
        float invaS = 1.0f / fmaxf(sqrtf(acc[0]), 1e-8f);
        float invaC = 1.0f / fmaxf(sqrtf(acc[1]), 1e-8f);
        int baseS = (i * (191 - i)) / 2 - i - 1;   // tri idx = baseS + j
#pragma unroll
        for (int m = 0; m < 4; m++) {
            float invb = 1.0f / fmaxf(sqrtf(acc[2 + m]), 1e-8f);
            float sc = acc[10 + m] * invaC * invb;          // neg sim
            neg[i * NROWS + j0 + m] = sc;
            wsn += sc; wmn = fminf(wmn, sc);
            if (j0 + m > i) {                               // pos sim (S)
                float ss = acc[6 + m] * invaS * invb;
                pos[baseS + j0 + m] = ss;
                wsp += ss; wmx = fmaxf(wmx, ss);
            }
        }
        float invaA = 1.0f / fmaxf(sqrtf(accA[0]), 1e-8f);
        int baseA = (ia * (191 - ia)) / 2 - ia - 1;
#pragma unroll
        for (int m = 0; m < 4; m++) {
            if (ja0 + m > ia) {                             // pos sim (A)
                float invb = 1.0f / fmaxf(sqrtf(accA[1 + m]), 1e-8f);
                float sa = accA[5 + m] * invaA * invb;
                pos[NPAIR + baseA + ja0 + m] = sa;
                wsp += sa; wmx = fmaxf(wmx, sa);
            }
        }
        sSp[wave] = wsp; sSn[wave] = wsn; sMx[wave] = wmx; sMn[wave] = wmn;
    }
    __syncthreads();
    if (tid == 0) {
        slotSp[blockIdx.x] = sSp[0] + sSp[1] + sSp[2] + sSp[3];
        slotSn[blockIdx.x] = sSn[0] + sSn[1] + sSn[2] + sSn[3];
        slotMx[blockIdx.x] = fmaxf(fmaxf(sMx[0], sMx[1]), fmaxf(sMx[2], sMx[3]));
        slotMn[blockIdx.x] = fminf(fminf(sMn[0], sMn[1]), fminf(sMn[2], sMn[3]));
    }
}

// ---- K2: single-block finalize: fp64 slot reduce + analytic hinge ----------
// sum max(0, n-p+T) = P*Sn - Q*Sp + P*Q*T + sum relu(p - T - n)
// (correction exactly 0 unless pmax - nmin > T; exact fallback kept)
__global__ __launch_bounds__(256) void final_kernel(
    const float* __restrict__ pos, const float* __restrict__ neg,
    const float* __restrict__ slotSp, const float* __restrict__ slotSn,
    const float* __restrict__ slotMx, const float* __restrict__ slotMn,
    float* __restrict__ out)
{
    __shared__ double rsp[4], rsn[4], redd[4];
    __shared__ float  rmx[4], rmn[4];
    __shared__ double bcd[2];
    __shared__ float  bnmin;
    __shared__ int    rare;

    int tid  = threadIdx.x;
    int wave = tid >> 6, lane = tid & 63;

    double sp = 0.0, sn = 0.0;
    float mx = -INFINITY, mn = INFINITY;
    for (int f = tid; f < NBLK; f += 256) {
        sp += (double)slotSp[f];
        sn += (double)slotSn[f];
        mx = fmaxf(mx, slotMx[f]);
        mn = fminf(mn, slotMn[f]);
    }
    for (int off = 32; off; off >>= 1) {
        sp += __shfl_down(sp, off);
        sn += __shfl_down(sn, off);
        mx = fmaxf(mx, __shfl_down(mx, off));
        mn = fminf(mn, __shfl_down(mn, off));
    }
    if (lane == 0) { rsp[wave] = sp; rsn[wave] = sn;
                     rmx[wave] = mx; rmn[wave] = mn; }
    __syncthreads();
    if (tid == 0) {
        bcd[0] = rsp[0] + rsp[1] + rsp[2] + rsp[3];          // Sp
        bcd[1] = rsn[0] + rsn[1] + rsn[2] + rsn[3];          // Sn
        float pm = fmaxf(fmaxf(rmx[0], rmx[1]), fmaxf(rmx[2], rmx[3]));
        float nm = fminf(fminf(rmn[0], rmn[1]), fminf(rmn[2], rmn[3]));
        bnmin = nm;
        rare = (pm - nm > THRESH) ? 1 : 0;
    }
    __syncthreads();

    double corr = 0.0;
    if (rare) {                                              // exact fallback
        float nmv = bnmin;
        for (int p = tid; p < PTOT; p += 256) {
            float pv = pos[p];
            if (pv - nmv > THRESH) {
                for (int q = 0; q < QTOT; q++) {
                    float d = pv - THRESH - neg[q];
                    if (d > 0.f) corr += (double)d;
                }
            }
        }
    }
    for (int off = 32; off; off >>= 1) corr += __shfl_down(corr, off);
    if (lane == 0) redd[wave] = corr;
    __syncthreads();
    if (tid == 0) {
        corr = redd[0] + redd[1] + redd[2] + redd[3];
        double PQ = (double)PTOT * (double)QTOT;
        double total = (double)PTOT * bcd[1] - (double)QTOT * bcd[0]
                     + PQ * (double)THRESH + corr;
        out[0] = (float)(total / PQ);
    }
}

extern "C" void kernel_launch(void* const* d_in, const int* in_sizes, int n_in,
                              void* d_out, int out_size, void* d_ws, size_t ws_size,
                              hipStream_t stream)
{
    const float* stereos  = (const float*)d_in[0];
    const float* astereos = (const float*)d_in[1];

    char* ws = (char*)d_ws;
    float* pos    = (float*)ws;
    float* neg    = (float*)(ws + 36480);
    float* slotSp = (float*)(ws + 73344);
    float* slotSn = (float*)(ws + 75648);
    float* slotMx = (float*)(ws + 77952);
    float* slotMn = (float*)(ws + 80256);
    float* out    = (float*)d_out;

    gram_kernel<<<NBLK, 256, 0, stream>>>(stereos, astereos, pos, neg,
                                          slotSp, slotSn, slotMx, slotMn);
    final_kernel<<<1, 256, 0, stream>>>(pos, neg, slotSp, slotSn,
                                        slotMx, slotMn, out);
}